// Round 5
// baseline (7654.373 us; speedup 1.0000x reference)
//
#include <hip/hip_runtime.h>
#include <hip/hip_fp16.h>

typedef _Float16 f16x8 __attribute__((ext_vector_type(8)));
typedef float f32x4 __attribute__((ext_vector_type(4)));
typedef unsigned short u16x8 __attribute__((ext_vector_type(8)));
typedef unsigned short ushort_t;
typedef unsigned int uint32;
typedef uint32 u32x4 __attribute__((ext_vector_type(4)));
typedef uint32 u32x2 __attribute__((ext_vector_type(2)));

constexpr size_t BTH = 128ull * 1024ull * 512ull;  // 67108864

__device__ __forceinline__ ushort_t f2h(float f) {
  return __half_as_ushort(__float2half(f));
}

// ---- tagged-word communication (fast = sc0 only -> local XCD L2; slow = sc0 sc1 -> LLC) ----
__device__ __forceinline__ u32x4 ld4t(const uint32* p, bool fast) {
  u32x4 r;
  if (fast) asm volatile("global_load_dwordx4 %0, %1, off sc0" : "=v"(r) : "v"(p));
  else      asm volatile("global_load_dwordx4 %0, %1, off sc0 sc1" : "=v"(r) : "v"(p));
  return r;
}
__device__ __forceinline__ void st1t(uint32* p, uint32 v, bool fast) {
  if (fast) asm volatile("global_store_dword %0, %1, off sc0" :: "v"(p), "v"(v) : "memory");
  else      asm volatile("global_store_dword %0, %1, off sc0 sc1" :: "v"(p), "v"(v) : "memory");
}
__device__ __forceinline__ void waitvm0() {
  asm volatile("s_waitcnt vmcnt(0)" ::: "memory");
  __builtin_amdgcn_sched_barrier(0);
}

// ---- pre-pass: x fp32 [b][t][k] -> fp16 [t][b][k] (round-2 layout, direct f16x8 reads) ----
__global__ void cvt_xT(const float* __restrict__ x, ushort_t* __restrict__ xT) {
  int row = blockIdx.x * 4 + (threadIdx.x >> 6);   // row = b*1024 + t
  int lane = threadIdx.x & 63;
  int b = row >> 10, t = row & 1023;
  const float* src = x + (size_t)row * 512 + lane * 8;
  float4 f0 = *(const float4*)src;
  float4 f1 = *(const float4*)(src + 4);
  u16x8 u;
  u[0] = f2h(f0.x); u[1] = f2h(f0.y); u[2] = f2h(f0.z); u[3] = f2h(f0.w);
  u[4] = f2h(f1.x); u[5] = f2h(f1.y); u[6] = f2h(f1.z); u[7] = f2h(f1.w);
  *(u16x8*)(xT + ((size_t)t * 128 + b) * 512 + lane * 8) = u;
}

// ---- main persistent recurrence kernel ----
// EXACT round-2 protocol skeleton (poll at loop top, immediate check, 2 barriers/step,
// produce-then-out, x_gemm(t+1) at step end). Single change: Wi/Wh B-fragments are
// extracted to VGPRs after the LDS preload; hls/gst live in a SEPARATE LDS region
// (no aliasing). All spins bounded (wedge -> fast wrong answer, never a hang).
template<bool XPRE>
__global__ __launch_bounds__(256, 1)
void lstm_rec(const float* __restrict__ x,
              const ushort_t* __restrict__ xT,
              const float* __restrict__ h0,
              const float* __restrict__ c0,
              const float* __restrict__ Wi,
              const float* __restrict__ bi,
              const float* __restrict__ Wh,
              const float* __restrict__ bh,
              float* __restrict__ out,
              uint32* __restrict__ hbuf,    // [2*8][8192] tagged u32 words
              uint32* __restrict__ ctrl)    // [0..7] per-xcd cnt, [8] arrival, [9] barrier
{
  extern __shared__ char smem[];
  ushort_t* Wis = (ushort_t*)smem;                 // [64][512] fp16, swizzled (preload only)
  ushort_t* Whs = (ushort_t*)(smem + 65536);       // [64][512]
  ushort_t* hls = (ushort_t*)(smem + 131072);      // [16][512] fp16, swizzled (separate!)
  float*    gst = (float*)(smem + 147456);         // 4 waves * 280 floats
  __shared__ int s_rg, s_cg, s_fast;

  const int tid = threadIdx.x;
  const int lane = tid & 63;
  const int w = tid >> 6;
  const int l15 = lane & 15;
  const int hi = lane >> 4;

  // ---------- registration: discover physical XCD, form rowgroups (bounded wait) ----------
  if (tid == 0) {
    uint32 xcc;
    asm volatile("s_getreg_b32 %0, hwreg(HW_REG_XCC_ID)" : "=s"(xcc));
    xcc &= 7u;
    uint32 rin = __hip_atomic_fetch_add(&ctrl[xcc], 1u, __ATOMIC_RELAXED, __HIP_MEMORY_SCOPE_AGENT);
    uint32 ar  = __hip_atomic_fetch_add(&ctrl[8],   1u, __ATOMIC_RELAXED, __HIP_MEMORY_SCOPE_AGENT);
    __hip_atomic_fetch_add(&ctrl[9], 1u, __ATOMIC_ACQ_REL, __HIP_MEMORY_SCOPE_AGENT);
    int spin = 0;
    while (__hip_atomic_load(&ctrl[9], __ATOMIC_ACQUIRE, __HIP_MEMORY_SCOPE_AGENT) < 256u) {
      if (++spin > (1 << 20)) break;
      __builtin_amdgcn_s_sleep(2);
    }
    bool bal = (spin <= (1 << 20));
    for (int i = 0; i < 8; ++i)
      bal &= (__hip_atomic_load(&ctrl[i], __ATOMIC_RELAXED, __HIP_MEMORY_SCOPE_AGENT) == 32u);
    if (bal) { s_rg = (int)xcc;       s_cg = (int)rin;      s_fast = 1; }
    else     { s_rg = (int)(ar >> 5); s_cg = (int)(ar & 31); s_fast = 0; }
  }
  __syncthreads();
  const int rg = s_rg, cg = s_cg;
  const bool fast = (s_fast != 0);
  const int rowbase = rg << 4;
  const int colbase = cg << 4;

  const int myrow = rowbase + l15;
  const int mycol = colbase + (w << 2) + hi;

  // ---------- h0 -> tagged words (tag 1, parity 0) ASAP (peers wait on this) ----------
  uint32* wr0 = hbuf + ((size_t)rg << 13) + (l15 << 9) + mycol;        // parity 0
  uint32* wr1 = hbuf + ((size_t)(8 + rg) << 13) + (l15 << 9) + mycol;  // parity 1
  st1t(wr0, (1u << 16) | (uint32)f2h(h0[myrow * 512 + mycol]), fast);

  // ---------- weight preload: fp32 global -> fp16 LDS, [vcol][k] XOR-swizzled ----------
  {
    const int j4 = (tid & 3) << 2;
    const int q  = (tid >> 2) & 3;
    const int kb = tid >> 4;
    const int gc = (q << 9) + colbase + j4;
    #pragma unroll 1
    for (int i = 0; i < 32; ++i) {
      int k = kb + (i << 4);
      float4 wi4 = *(const float4*)(Wi + (size_t)k * 2048 + gc);
      float4 wh4 = *(const float4*)(Wh + (size_t)k * 2048 + gc);
      #pragma unroll
      for (int m = 0; m < 4; ++m) {
        int v2 = ((j4 + m) << 2) + q;
        int idx = (v2 << 9) + ((((k >> 3) ^ (v2 & 7)) << 3) | (k & 7));
        Wis[idx] = f2h(((const float*)&wi4)[m]);
        Whs[idx] = f2h(((const float*)&wh4)[m]);
      }
    }
  }
  __syncthreads();

  // ---------- extract B-fragments to VGPRs (held for the whole kernel) ----------
  const int myv = (w << 4) + l15;
  const int vsw = myv & 7;
  const int rsw = l15 & 7;
  f16x8 bWi[16], bWh[16];
  {
    const ushort_t* wiB = Wis + (myv << 9);
    const ushort_t* whB = Whs + (myv << 9);
    #pragma unroll
    for (int kk = 0; kk < 16; ++kk) {
      const int off = (((kk << 2) + hi) ^ vsw) << 3;
      bWi[kk] = *(const f16x8*)(wiB + off);
      bWh[kk] = *(const f16x8*)(whB + off);
    }
  }

  const int mygc = ((myv & 3) << 9) + colbase + (myv >> 2);
  const float biasv = bi[mygc] + bh[mygc];
  float c = c0[myrow * 512 + mycol];

  const size_t xT_lane = (size_t)(rowbase + l15) * 512 + (hi << 3);
  const float* xf_lane = x + ((size_t)(rowbase + l15) * 1024) * 512 + (hi << 3);
  const ushort_t* hrow = hls + (l15 << 9);

  // x * Wi + bias for step t -> f32x4 (B operand from VGPRs; off the h critical path)
  auto x_gemm = [&](int t) -> f32x4 {
    f32x4 a0 = {biasv, biasv, biasv, biasv}, a1 = {0.f, 0.f, 0.f, 0.f};
    if (XPRE) {
      const ushort_t* xrow = xT + (((size_t)t) << 16) + xT_lane;
      #pragma unroll
      for (int kk = 0; kk < 16; ++kk) {
        f16x8 ax = *(const f16x8*)(xrow + (kk << 5));
        if (kk & 1) a1 = __builtin_amdgcn_mfma_f32_16x16x32_f16(ax, bWi[kk], a1, 0, 0, 0);
        else        a0 = __builtin_amdgcn_mfma_f32_16x16x32_f16(ax, bWi[kk], a0, 0, 0, 0);
      }
    } else {
      const float* xrf = xf_lane + (((size_t)t) << 9);
      #pragma unroll
      for (int kk = 0; kk < 16; ++kk) {
        const int k0 = kk << 5;
        float4 xa = *(const float4*)(xrf + k0);
        float4 xb = *(const float4*)(xrf + k0 + 4);
        f16x8 ax;
        ax[0] = (_Float16)xa.x; ax[1] = (_Float16)xa.y;
        ax[2] = (_Float16)xa.z; ax[3] = (_Float16)xa.w;
        ax[4] = (_Float16)xb.x; ax[5] = (_Float16)xb.y;
        ax[6] = (_Float16)xb.z; ax[7] = (_Float16)xb.w;
        if (kk & 1) a1 = __builtin_amdgcn_mfma_f32_16x16x32_f16(ax, bWi[kk], a1, 0, 0, 0);
        else        a0 = __builtin_amdgcn_mfma_f32_16x16x32_f16(ax, bWi[kk], a0, 0, 0, 0);
      }
    }
    return a0 + a1;
  };

  f32x4 axb = x_gemm(0);

  const uint32* rd0 = hbuf + ((size_t)rg << 13) + (tid << 2);
  const uint32* rd1 = hbuf + ((size_t)(8 + rg) << 13) + (tid << 2);

  for (int t = 0; t < 1024; ++t) {
    // ---- poll + stage h(t): tagged words, parity t&1, expected tag t+1 (round-2 form) ----
    {
      const uint32* base = (t & 1) ? rd1 : rd0;
      const uint32 etag = (uint32)(t + 1);
      u32x4 v[8];
      #pragma unroll
      for (int j = 0; j < 8; ++j) v[j] = ld4t(base + (j << 10), fast);
      waitvm0();
      #pragma unroll
      for (int j = 0; j < 8; ++j) {
        u32x4 vv = v[j];
        int spin = 0;
        while (((vv[0] >> 16) != etag) | ((vv[1] >> 16) != etag) |
               ((vv[2] >> 16) != etag) | ((vv[3] >> 16) != etag)) {
          if (++spin > (1 << 18)) break;    // wedge -> proceed (wrong answer, no hang)
          __builtin_amdgcn_s_sleep(1);
          vv = ld4t(base + (j << 10), fast);
          waitvm0();
        }
        const int w0 = (j << 10) + (tid << 2);     // word idx: row = w0>>9, col = w0&511
        const int r = w0 >> 9;
        const int c32 = (w0 & 511) >> 1;           // even
        u32x2 p;
        p[0] = (vv[0] & 0xffffu) | (vv[1] << 16);
        p[1] = (vv[2] & 0xffffu) | (vv[3] << 16);
        *(u32x2*)((uint32*)hls + (r << 8) + (((c32 >> 2) ^ (r & 7)) << 2) + (c32 & 3)) = p;
      }
    }
    __syncthreads();

    // ---- gates = axb + h*Wh (16 fp16 MFMAs, fp32 accum; B from VGPRs) ----
    f32x4 aH0 = axb, aH1 = {0.f, 0.f, 0.f, 0.f};
    #pragma unroll
    for (int kk = 0; kk < 16; ++kk) {
      f16x8 ah = *(const f16x8*)(hrow + ((((kk << 2) + hi) ^ rsw) << 3));
      if (kk & 1) aH1 = __builtin_amdgcn_mfma_f32_16x16x32_f16(ah, bWh[kk], aH1, 0, 0, 0);
      else        aH0 = __builtin_amdgcn_mfma_f32_16x16x32_f16(ah, bWh[kk], aH0, 0, 0, 0);
    }
    f32x4 acc = aH0 + aH1;
    __syncthreads();   // hls reads done -> next iteration's staging may overwrite

    // ---- gate exchange: per-WAVE LDS slab (in-order DS, no barrier needed) ----
    {
      float* gp = gst + w * 280 + l15 * 17 + (hi << 2);
      gp[0] = acc[0]; gp[1] = acc[1]; gp[2] = acc[2]; gp[3] = acc[3];
    }
    const float* gq = gst + w * 280 + (hi << 2) * 17 + l15;
    const float gI = gq[0], gF = gq[17], gG = gq[34], gO = gq[51];

    const float ig = 1.f / (1.f + __expf(-gI));
    const float fg = 1.f / (1.f + __expf(-gF));
    const float gg = 1.f - 2.f / (1.f + __expf(2.f * gG));
    const float og = 1.f / (1.f + __expf(-gO));
    c = fg * c + ig * gg;
    const float hv = og * (1.f - 2.f / (1.f + __expf(2.f * c)));

    // ---- produce h(t+1) FIRST (peers' critical path), then out, then next x GEMM ----
    if (t < 1023) {
      uint32 word = ((uint32)(t + 2) << 16) | (uint32)f2h(hv);
      st1t((t & 1) ? wr0 : wr1, word, fast);
    }
    out[((size_t)myrow << 19) + ((size_t)t << 9) + mycol] = hv;
    if (t == 1023) {
      out[BTH + (size_t)myrow * 512 + mycol] = hv;            // hy
      out[BTH + 65536 + (size_t)myrow * 512 + mycol] = c;     // cy
    }
    if (t < 1023) axb = x_gemm(t + 1);
  }
}

extern "C" void kernel_launch(void* const* d_in, const int* in_sizes, int n_in,
                              void* d_out, int out_size, void* d_ws, size_t ws_size,
                              hipStream_t stream) {
  const float* x  = (const float*)d_in[0];
  const float* h0 = (const float*)d_in[1];
  const float* c0 = (const float*)d_in[2];
  // d_in[3] = ctx (unused by reference forward)
  const float* Wi = (const float*)d_in[4];
  const float* bi = (const float*)d_in[5];
  const float* Wh = (const float*)d_in[6];
  const float* bh = (const float*)d_in[7];
  float* out = (float*)d_out;

  char* ws = (char*)d_ws;
  uint32* ctrl = (uint32*)ws;                        // 64 B used
  uint32* hbuf = (uint32*)(ws + 4096);               // 512 KB tagged h
  ushort_t* xT = (ushort_t*)(ws + (1u << 20));       // 128 MB fp16 [t][b][k]
  const size_t need_xpre = (1ull << 20) + 134217728ull;
  const bool xpre = ws_size >= need_xpre;

  // zero ctrl + hbuf tags every launch (tags must not survive across replays)
  hipMemsetAsync(ws, 0, 4096 + 524288, stream);

  if (xpre) {
    cvt_xT<<<dim3(32768), dim3(256), 0, stream>>>(x, xT);
  }

  const int LDS_BYTES = 147456 + 4480;               // 151,936 B (no aliasing)
  if (xpre) {
    hipFuncSetAttribute((const void*)lstm_rec<true>,
                        hipFuncAttributeMaxDynamicSharedMemorySize, LDS_BYTES);
    void* args[] = {(void*)&x, (void*)&xT, (void*)&h0, (void*)&c0, (void*)&Wi,
                    (void*)&bi, (void*)&Wh, (void*)&bh, (void*)&out,
                    (void*)&hbuf, (void*)&ctrl};
    hipLaunchCooperativeKernel((const void*)lstm_rec<true>, dim3(256), dim3(256),
                               args, LDS_BYTES, stream);
  } else {
    hipFuncSetAttribute((const void*)lstm_rec<false>,
                        hipFuncAttributeMaxDynamicSharedMemorySize, LDS_BYTES);
    void* args[] = {(void*)&x, (void*)&xT, (void*)&h0, (void*)&c0, (void*)&Wi,
                    (void*)&bi, (void*)&Wh, (void*)&bh, (void*)&out,
                    (void*)&hbuf, (void*)&ctrl};
    hipLaunchCooperativeKernel((const void*)lstm_rec<false>, dim3(256), dim3(256),
                               args, LDS_BYTES, stream);
  }
}

// Round 7
// 7596.867 us; speedup vs baseline: 1.0076x; 1.0076x over previous
//
#include <hip/hip_runtime.h>
#include <hip/hip_fp16.h>

typedef _Float16 f16x8 __attribute__((ext_vector_type(8)));
typedef float f32x4 __attribute__((ext_vector_type(4)));
typedef unsigned short u16x8 __attribute__((ext_vector_type(8)));
typedef unsigned short ushort_t;
typedef unsigned int uint32;
typedef uint32 u32x4 __attribute__((ext_vector_type(4)));
typedef uint32 u32x2 __attribute__((ext_vector_type(2)));

constexpr size_t BTH = 128ull * 1024ull * 512ull;  // 67108864

__device__ __forceinline__ ushort_t f2h(float f) {
  return __half_as_ushort(__float2half(f));
}

// ---- tagged-word communication (fast = sc0 only -> local XCD L2; slow = sc0 sc1 -> LLC) ----
__device__ __forceinline__ u32x4 ld4t(const uint32* p, bool fast) {
  u32x4 r;
  if (fast) asm volatile("global_load_dwordx4 %0, %1, off sc0" : "=v"(r) : "v"(p));
  else      asm volatile("global_load_dwordx4 %0, %1, off sc0 sc1" : "=v"(r) : "v"(p));
  return r;
}
__device__ __forceinline__ void st1t(uint32* p, uint32 v, bool fast) {
  if (fast) asm volatile("global_store_dword %0, %1, off sc0" :: "v"(p), "v"(v) : "memory");
  else      asm volatile("global_store_dword %0, %1, off sc0 sc1" :: "v"(p), "v"(v) : "memory");
}
__device__ __forceinline__ void waitvm0() {
  asm volatile("s_waitcnt vmcnt(0)" ::: "memory");
  __builtin_amdgcn_sched_barrier(0);
}

// ---- pre-pass: x fp32 [b][t][k] -> fp16 [t][b][k] ----
__global__ void cvt_xT(const float* __restrict__ x, ushort_t* __restrict__ xT) {
  int row = blockIdx.x * 4 + (threadIdx.x >> 6);   // row = b*1024 + t
  int lane = threadIdx.x & 63;
  int b = row >> 10, t = row & 1023;
  const float* src = x + (size_t)row * 512 + lane * 8;
  float4 f0 = *(const float4*)src;
  float4 f1 = *(const float4*)(src + 4);
  u16x8 u;
  u[0] = f2h(f0.x); u[1] = f2h(f0.y); u[2] = f2h(f0.z); u[3] = f2h(f0.w);
  u[4] = f2h(f1.x); u[5] = f2h(f1.y); u[6] = f2h(f1.z); u[7] = f2h(f1.w);
  *(u16x8*)(xT + ((size_t)t * 128 + b) * 512 + lane * 8) = u;
}

// ---- main persistent recurrence kernel ----
// EXACT round-5 skeleton (which passed) with ONE change: SELF-MASK — a block never
// waits on / unpacks its OWN 16 columns from the slab; each thread writes its own h
// value directly into LDS at produce time. This removes the guaranteed-stale self-poll
// (own store ~50ns before own poll) that serialized up to 8 L2 round trips per step.
template<bool XPRE>
__global__ __launch_bounds__(256, 1)
void lstm_rec(const float* __restrict__ x,
              const ushort_t* __restrict__ xT,
              const float* __restrict__ h0,
              const float* __restrict__ c0,
              const float* __restrict__ Wi,
              const float* __restrict__ bi,
              const float* __restrict__ Wh,
              const float* __restrict__ bh,
              float* __restrict__ out,
              uint32* __restrict__ hbuf,    // [2*8][8192] tagged u32 words
              uint32* __restrict__ ctrl)    // [0..7] per-xcd cnt, [8] arrival, [9] barrier
{
  extern __shared__ char smem[];
  ushort_t* Wis = (ushort_t*)smem;                 // [64][512] fp16, swizzled (preload only)
  ushort_t* Whs = (ushort_t*)(smem + 65536);       // [64][512]
  ushort_t* hls = (ushort_t*)(smem + 131072);      // [16][512] fp16, swizzled (separate)
  float*    gst = (float*)(smem + 147456);         // 4 waves * 280 floats
  __shared__ int s_rg, s_cg, s_fast;

  const int tid = threadIdx.x;
  const int lane = tid & 63;
  const int w = tid >> 6;
  const int l15 = lane & 15;
  const int hi = lane >> 4;

  // ---------- registration: discover physical XCD, form rowgroups (bounded wait) ----------
  if (tid == 0) {
    uint32 xcc;
    asm volatile("s_getreg_b32 %0, hwreg(HW_REG_XCC_ID)" : "=s"(xcc));
    xcc &= 7u;
    uint32 rin = __hip_atomic_fetch_add(&ctrl[xcc], 1u, __ATOMIC_RELAXED, __HIP_MEMORY_SCOPE_AGENT);
    uint32 ar  = __hip_atomic_fetch_add(&ctrl[8],   1u, __ATOMIC_RELAXED, __HIP_MEMORY_SCOPE_AGENT);
    __hip_atomic_fetch_add(&ctrl[9], 1u, __ATOMIC_ACQ_REL, __HIP_MEMORY_SCOPE_AGENT);
    int spin = 0;
    while (__hip_atomic_load(&ctrl[9], __ATOMIC_ACQUIRE, __HIP_MEMORY_SCOPE_AGENT) < 256u) {
      if (++spin > (1 << 20)) break;
      __builtin_amdgcn_s_sleep(2);
    }
    bool bal = (spin <= (1 << 20));
    for (int i = 0; i < 8; ++i)
      bal &= (__hip_atomic_load(&ctrl[i], __ATOMIC_RELAXED, __HIP_MEMORY_SCOPE_AGENT) == 32u);
    if (bal) { s_rg = (int)xcc;       s_cg = (int)rin;      s_fast = 1; }
    else     { s_rg = (int)(ar >> 5); s_cg = (int)(ar & 31); s_fast = 0; }
  }
  __syncthreads();
  const int rg = s_rg, cg = s_cg;
  const bool fast = (s_fast != 0);
  const int rowbase = rg << 4;
  const int colbase = cg << 4;

  const int myrow = rowbase + l15;
  const int mycol = colbase + (w << 2) + hi;

  // own-value LDS slot (fp16 element index inside swizzled hls)
  const int c32s = mycol >> 1;
  const int own_u32 = (l15 << 8) + (((c32s >> 2) ^ (l15 & 7)) << 2) + (c32s & 3);
  const int own_e16 = (own_u32 << 1) | (mycol & 1);

  // ---------- h0 -> tagged words (tag 1, parity 0) ASAP + own LDS copy ----------
  uint32* wr0 = hbuf + ((size_t)rg << 13) + (l15 << 9) + mycol;        // parity 0
  uint32* wr1 = hbuf + ((size_t)(8 + rg) << 13) + (l15 << 9) + mycol;  // parity 1
  {
    const ushort_t h0h = f2h(h0[myrow * 512 + mycol]);
    st1t(wr0, (1u << 16) | (uint32)h0h, fast);
    hls[own_e16] = h0h;
  }

  // ---------- weight preload: fp32 global -> fp16 LDS, [vcol][k] XOR-swizzled ----------
  {
    const int j4 = (tid & 3) << 2;
    const int q  = (tid >> 2) & 3;
    const int kb = tid >> 4;
    const int gc = (q << 9) + colbase + j4;
    #pragma unroll 1
    for (int i = 0; i < 32; ++i) {
      int k = kb + (i << 4);
      float4 wi4 = *(const float4*)(Wi + (size_t)k * 2048 + gc);
      float4 wh4 = *(const float4*)(Wh + (size_t)k * 2048 + gc);
      #pragma unroll
      for (int m = 0; m < 4; ++m) {
        int v2 = ((j4 + m) << 2) + q;
        int idx = (v2 << 9) + ((((k >> 3) ^ (v2 & 7)) << 3) | (k & 7));
        Wis[idx] = f2h(((const float*)&wi4)[m]);
        Whs[idx] = f2h(((const float*)&wh4)[m]);
      }
    }
  }
  __syncthreads();

  // ---------- extract B-fragments to VGPRs (held for the whole kernel) ----------
  const int myv = (w << 4) + l15;
  const int vsw = myv & 7;
  const int rsw = l15 & 7;
  f16x8 bWi[16], bWh[16];
  {
    const ushort_t* wiB = Wis + (myv << 9);
    const ushort_t* whB = Whs + (myv << 9);
    #pragma unroll
    for (int kk = 0; kk < 16; ++kk) {
      const int off = (((kk << 2) + hi) ^ vsw) << 3;
      bWi[kk] = *(const f16x8*)(wiB + off);
      bWh[kk] = *(const f16x8*)(whB + off);
    }
  }

  const int mygc = ((myv & 3) << 9) + colbase + (myv >> 2);
  const float biasv = bi[mygc] + bh[mygc];
  float c = c0[myrow * 512 + mycol];

  const size_t xT_lane = (size_t)(rowbase + l15) * 512 + (hi << 3);
  const float* xf_lane = x + ((size_t)(rowbase + l15) * 1024) * 512 + (hi << 3);
  const ushort_t* hrow = hls + (l15 << 9);

  // x * Wi + bias for step t -> f32x4 (B operand from VGPRs; off the h critical path)
  auto x_gemm = [&](int t) -> f32x4 {
    f32x4 a0 = {biasv, biasv, biasv, biasv}, a1 = {0.f, 0.f, 0.f, 0.f};
    if (XPRE) {
      const ushort_t* xrow = xT + (((size_t)t) << 16) + xT_lane;
      #pragma unroll
      for (int kk = 0; kk < 16; ++kk) {
        f16x8 ax = *(const f16x8*)(xrow + (kk << 5));
        if (kk & 1) a1 = __builtin_amdgcn_mfma_f32_16x16x32_f16(ax, bWi[kk], a1, 0, 0, 0);
        else        a0 = __builtin_amdgcn_mfma_f32_16x16x32_f16(ax, bWi[kk], a0, 0, 0, 0);
      }
    } else {
      const float* xrf = xf_lane + (((size_t)t) << 9);
      #pragma unroll
      for (int kk = 0; kk < 16; ++kk) {
        const int k0 = kk << 5;
        float4 xa = *(const float4*)(xrf + k0);
        float4 xb = *(const float4*)(xrf + k0 + 4);
        f16x8 ax;
        ax[0] = (_Float16)xa.x; ax[1] = (_Float16)xa.y;
        ax[2] = (_Float16)xa.z; ax[3] = (_Float16)xa.w;
        ax[4] = (_Float16)xb.x; ax[5] = (_Float16)xb.y;
        ax[6] = (_Float16)xb.z; ax[7] = (_Float16)xb.w;
        if (kk & 1) a1 = __builtin_amdgcn_mfma_f32_16x16x32_f16(ax, bWi[kk], a1, 0, 0, 0);
        else        a0 = __builtin_amdgcn_mfma_f32_16x16x32_f16(ax, bWi[kk], a0, 0, 0, 0);
      }
    }
    return a0 + a1;
  };

  f32x4 axb = x_gemm(0);

  const uint32* rd0 = hbuf + ((size_t)rg << 13) + (tid << 2);
  const uint32* rd1 = hbuf + ((size_t)(8 + rg) << 13) + (tid << 2);

  for (int t = 0; t < 1024; ++t) {
    // ---- poll + stage h(t): tagged words; SELF-MASKED (own cols never waited on) ----
    {
      const uint32* base = (t & 1) ? rd1 : rd0;
      const uint32 etag = (uint32)(t + 1);
      u32x4 v[8];
      #pragma unroll
      for (int j = 0; j < 8; ++j) v[j] = ld4t(base + (j << 10), fast);
      waitvm0();
      #pragma unroll
      for (int j = 0; j < 8; ++j) {
        const int w0 = (j << 10) + (tid << 2);     // word idx: row = w0>>9, col = w0&511
        const int col0 = w0 & 511;
        const bool mine = ((col0 & ~15) == colbase);
        u32x4 vv = v[j];
        int spin = 0;
        while (!mine && (((vv[0] >> 16) != etag) | ((vv[1] >> 16) != etag) |
                         ((vv[2] >> 16) != etag) | ((vv[3] >> 16) != etag))) {
          if (++spin > (1 << 18)) break;    // wedge -> proceed (wrong answer, no hang)
          __builtin_amdgcn_s_sleep(1);
          vv = ld4t(base + (j << 10), fast);
          waitvm0();
        }
        if (!mine) {
          const int r = w0 >> 9;
          const int c32 = col0 >> 1;
          u32x2 p;
          p[0] = (vv[0] & 0xffffu) | (vv[1] << 16);
          p[1] = (vv[2] & 0xffffu) | (vv[3] << 16);
          *(u32x2*)((uint32*)hls + (r << 8) + (((c32 >> 2) ^ (r & 7)) << 2) + (c32 & 3)) = p;
        }
      }
    }
    __syncthreads();

    // ---- gates = axb + h*Wh (16 fp16 MFMAs, fp32 accum; B from VGPRs) ----
    f32x4 aH0 = axb, aH1 = {0.f, 0.f, 0.f, 0.f};
    #pragma unroll
    for (int kk = 0; kk < 16; ++kk) {
      f16x8 ah = *(const f16x8*)(hrow + ((((kk << 2) + hi) ^ rsw) << 3));
      if (kk & 1) aH1 = __builtin_amdgcn_mfma_f32_16x16x32_f16(ah, bWh[kk], aH1, 0, 0, 0);
      else        aH0 = __builtin_amdgcn_mfma_f32_16x16x32_f16(ah, bWh[kk], aH0, 0, 0, 0);
    }
    f32x4 acc = aH0 + aH1;
    __syncthreads();   // hls reads done -> next iteration's staging may overwrite

    // ---- gate exchange: per-WAVE LDS slab (in-order DS, no barrier needed) ----
    {
      float* gp = gst + w * 280 + l15 * 17 + (hi << 2);
      gp[0] = acc[0]; gp[1] = acc[1]; gp[2] = acc[2]; gp[3] = acc[3];
    }
    const float* gq = gst + w * 280 + (hi << 2) * 17 + l15;
    const float gI = gq[0], gF = gq[17], gG = gq[34], gO = gq[51];

    const float ig = 1.f / (1.f + __expf(-gI));
    const float fg = 1.f / (1.f + __expf(-gF));
    const float gg = 1.f - 2.f / (1.f + __expf(2.f * gG));
    const float og = 1.f / (1.f + __expf(-gO));
    c = fg * c + ig * gg;
    const float hv = og * (1.f - 2.f / (1.f + __expf(2.f * c)));
    const ushort_t hb = f2h(hv);

    // ---- produce h(t+1): peers via L2 tagged word, own value straight to LDS ----
    if (t < 1023) {
      uint32 word = ((uint32)(t + 2) << 16) | (uint32)hb;
      st1t((t & 1) ? wr0 : wr1, word, fast);
      hls[own_e16] = hb;               // own cols skipped by unpack next step
    }
    out[((size_t)myrow << 19) + ((size_t)t << 9) + mycol] = hv;
    if (t == 1023) {
      out[BTH + (size_t)myrow * 512 + mycol] = hv;            // hy
      out[BTH + 65536 + (size_t)myrow * 512 + mycol] = c;     // cy
    }
    if (t < 1023) axb = x_gemm(t + 1);
  }
}

extern "C" void kernel_launch(void* const* d_in, const int* in_sizes, int n_in,
                              void* d_out, int out_size, void* d_ws, size_t ws_size,
                              hipStream_t stream) {
  const float* x  = (const float*)d_in[0];
  const float* h0 = (const float*)d_in[1];
  const float* c0 = (const float*)d_in[2];
  // d_in[3] = ctx (unused by reference forward)
  const float* Wi = (const float*)d_in[4];
  const float* bi = (const float*)d_in[5];
  const float* Wh = (const float*)d_in[6];
  const float* bh = (const float*)d_in[7];
  float* out = (float*)d_out;

  char* ws = (char*)d_ws;
  uint32* ctrl = (uint32*)ws;                        // 64 B used
  uint32* hbuf = (uint32*)(ws + 4096);               // 512 KB tagged h
  ushort_t* xT = (ushort_t*)(ws + (1u << 20));       // 128 MB fp16 [t][b][k]
  const size_t need_xpre = (1ull << 20) + 134217728ull;
  const bool xpre = ws_size >= need_xpre;

  // zero ctrl + hbuf tags every launch (tags must not survive across replays)
  hipMemsetAsync(ws, 0, 4096 + 524288, stream);

  if (xpre) {
    cvt_xT<<<dim3(32768), dim3(256), 0, stream>>>(x, xT);
  }

  const int LDS_BYTES = 147456 + 4480;               // 151,936 B
  if (xpre) {
    hipFuncSetAttribute((const void*)lstm_rec<true>,
                        hipFuncAttributeMaxDynamicSharedMemorySize, LDS_BYTES);
    void* args[] = {(void*)&x, (void*)&xT, (void*)&h0, (void*)&c0, (void*)&Wi,
                    (void*)&bi, (void*)&Wh, (void*)&bh, (void*)&out,
                    (void*)&hbuf, (void*)&ctrl};
    hipLaunchCooperativeKernel((const void*)lstm_rec<true>, dim3(256), dim3(256),
                               args, LDS_BYTES, stream);
  } else {
    hipFuncSetAttribute((const void*)lstm_rec<false>,
                        hipFuncAttributeMaxDynamicSharedMemorySize, LDS_BYTES);
    void* args[] = {(void*)&x, (void*)&xT, (void*)&h0, (void*)&c0, (void*)&Wi,
                    (void*)&bi, (void*)&Wh, (void*)&bh, (void*)&out,
                    (void*)&hbuf, (void*)&ctrl};
    hipLaunchCooperativeKernel((const void*)lstm_rec<false>, dim3(256), dim3(256),
                               args, LDS_BYTES, stream);
  }
}

// Round 10
// 7541.491 us; speedup vs baseline: 1.0150x; 1.0073x over previous
//
#include <hip/hip_runtime.h>
#include <hip/hip_fp16.h>

typedef _Float16 f16x8 __attribute__((ext_vector_type(8)));
typedef float f32x4 __attribute__((ext_vector_type(4)));
typedef unsigned short u16x8 __attribute__((ext_vector_type(8)));
typedef unsigned short ushort_t;
typedef unsigned int uint32;
typedef uint32 u32x4 __attribute__((ext_vector_type(4)));
typedef uint32 u32x2 __attribute__((ext_vector_type(2)));

constexpr size_t BTH = 128ull * 1024ull * 512ull;  // 67108864

__device__ __forceinline__ ushort_t f2h(float f) {
  return __half_as_ushort(__float2half(f));
}

// ---- tagged-word communication (fast = sc0 only -> local XCD L2; slow = sc0 sc1 -> LLC) ----
__device__ __forceinline__ u32x4 ld4t(const uint32* p, bool fast) {
  u32x4 r;
  if (fast) asm volatile("global_load_dwordx4 %0, %1, off sc0" : "=v"(r) : "v"(p));
  else      asm volatile("global_load_dwordx4 %0, %1, off sc0 sc1" : "=v"(r) : "v"(p));
  return r;
}
__device__ __forceinline__ void st1t(uint32* p, uint32 v, bool fast) {
  if (fast) asm volatile("global_store_dword %0, %1, off sc0" :: "v"(p), "v"(v) : "memory");
  else      asm volatile("global_store_dword %0, %1, off sc0 sc1" :: "v"(p), "v"(v) : "memory");
}
__device__ __forceinline__ void waitvm0() {
  asm volatile("s_waitcnt vmcnt(0)" ::: "memory");
  __builtin_amdgcn_sched_barrier(0);
}

// ---- pre-pass: x fp32 [b][t][k] -> fp16 [t][b][k] ----
__global__ void cvt_xT(const float* __restrict__ x, ushort_t* __restrict__ xT) {
  int row = blockIdx.x * 4 + (threadIdx.x >> 6);   // row = b*1024 + t
  int lane = threadIdx.x & 63;
  int b = row >> 10, t = row & 1023;
  const float* src = x + (size_t)row * 512 + lane * 8;
  float4 f0 = *(const float4*)src;
  float4 f1 = *(const float4*)(src + 4);
  u16x8 u;
  u[0] = f2h(f0.x); u[1] = f2h(f0.y); u[2] = f2h(f0.z); u[3] = f2h(f0.w);
  u[4] = f2h(f1.x); u[5] = f2h(f1.y); u[6] = f2h(f1.z); u[7] = f2h(f1.w);
  *(u16x8*)(xT + ((size_t)t * 128 + b) * 512 + lane * 8) = u;
}

// unpack one passing chunk into swizzled hls (peers' words only)
#define UNPACK_CHUNK(J, VV)                                                        \
  do {                                                                             \
    const int w0_ = ((J) << 10) + (tid << 2);                                      \
    const int r_ = w0_ >> 9;                                                       \
    const int c32_ = (w0_ & 511) >> 1;                                             \
    u32x2 p_;                                                                      \
    p_[0] = ((VV)[0] & 0xffffu) | ((VV)[1] << 16);                                 \
    p_[1] = ((VV)[2] & 0xffffu) | ((VV)[3] << 16);                                 \
    *(u32x2*)((uint32*)hls + (r_ << 8) + (((c32_ >> 2) ^ (r_ & 7)) << 2) +         \
              (c32_ & 3)) = p_;                                                    \
  } while (0)

// ---- main persistent recurrence kernel ----
// EXACT round-7 skeleton (passing: polls issued AND drained at loop top, v[] consumed
// immediately — no asm-register liveness across heavy regions; x_gemm at tail).
// Single delta vs round 7: BATCHED retry — all failing chunks re-issued together with
// ONE waitvm0 per round, instead of 8 serialized per-chunk retry loops (~7 L2 RTs/step).
template<bool XPRE>
__global__ __launch_bounds__(256, 1)
void lstm_rec(const float* __restrict__ x,
              const ushort_t* __restrict__ xT,
              const float* __restrict__ h0,
              const float* __restrict__ c0,
              const float* __restrict__ Wi,
              const float* __restrict__ bi,
              const float* __restrict__ Wh,
              const float* __restrict__ bh,
              float* __restrict__ out,
              uint32* __restrict__ hbuf,    // [2*8][8192] tagged u32 words
              uint32* __restrict__ ctrl)    // [0..7] per-xcd cnt, [8] arrival, [9] barrier
{
  extern __shared__ char smem[];
  ushort_t* Wis = (ushort_t*)smem;                 // [64][512] fp16, swizzled (preload only)
  ushort_t* Whs = (ushort_t*)(smem + 65536);       // [64][512]
  ushort_t* hls = (ushort_t*)(smem + 131072);      // [16][512] fp16, swizzled (separate)
  float*    gst = (float*)(smem + 147456);         // 4 waves * 280 floats
  __shared__ int s_rg, s_cg, s_fast;

  const int tid = threadIdx.x;
  const int lane = tid & 63;
  const int w = tid >> 6;
  const int l15 = lane & 15;
  const int hi = lane >> 4;

  // ---------- registration: discover physical XCD, form rowgroups (bounded wait) ----------
  if (tid == 0) {
    uint32 xcc;
    asm volatile("s_getreg_b32 %0, hwreg(HW_REG_XCC_ID)" : "=s"(xcc));
    xcc &= 7u;
    uint32 rin = __hip_atomic_fetch_add(&ctrl[xcc], 1u, __ATOMIC_RELAXED, __HIP_MEMORY_SCOPE_AGENT);
    uint32 ar  = __hip_atomic_fetch_add(&ctrl[8],   1u, __ATOMIC_RELAXED, __HIP_MEMORY_SCOPE_AGENT);
    __hip_atomic_fetch_add(&ctrl[9], 1u, __ATOMIC_ACQ_REL, __HIP_MEMORY_SCOPE_AGENT);
    int spin = 0;
    while (__hip_atomic_load(&ctrl[9], __ATOMIC_ACQUIRE, __HIP_MEMORY_SCOPE_AGENT) < 256u) {
      if (++spin > (1 << 20)) break;
      __builtin_amdgcn_s_sleep(2);
    }
    bool bal = (spin <= (1 << 20));
    for (int i = 0; i < 8; ++i)
      bal &= (__hip_atomic_load(&ctrl[i], __ATOMIC_RELAXED, __HIP_MEMORY_SCOPE_AGENT) == 32u);
    if (bal) { s_rg = (int)xcc;       s_cg = (int)rin;      s_fast = 1; }
    else     { s_rg = (int)(ar >> 5); s_cg = (int)(ar & 31); s_fast = 0; }
  }
  __syncthreads();
  const int rg = s_rg, cg = s_cg;
  const bool fast = (s_fast != 0);
  const int rowbase = rg << 4;
  const int colbase = cg << 4;

  const int myrow = rowbase + l15;
  const int mycol = colbase + (w << 2) + hi;

  // own-value LDS slot (fp16 element index inside swizzled hls)
  const int c32s = mycol >> 1;
  const int own_u32 = (l15 << 8) + (((c32s >> 2) ^ (l15 & 7)) << 2) + (c32s & 3);
  const int own_e16 = (own_u32 << 1) | (mycol & 1);

  // ---------- h0 -> tagged words (tag 1, parity 0) ASAP + own LDS copy ----------
  uint32* wr0 = hbuf + ((size_t)rg << 13) + (l15 << 9) + mycol;        // parity 0
  uint32* wr1 = hbuf + ((size_t)(8 + rg) << 13) + (l15 << 9) + mycol;  // parity 1
  {
    const ushort_t h0h = f2h(h0[myrow * 512 + mycol]);
    st1t(wr0, (1u << 16) | (uint32)h0h, fast);
    hls[own_e16] = h0h;
  }

  // ---------- weight preload: fp32 global -> fp16 LDS, [vcol][k] XOR-swizzled ----------
  {
    const int j4 = (tid & 3) << 2;
    const int q  = (tid >> 2) & 3;
    const int kb = tid >> 4;
    const int gc = (q << 9) + colbase + j4;
    #pragma unroll 1
    for (int i = 0; i < 32; ++i) {
      int k = kb + (i << 4);
      float4 wi4 = *(const float4*)(Wi + (size_t)k * 2048 + gc);
      float4 wh4 = *(const float4*)(Wh + (size_t)k * 2048 + gc);
      #pragma unroll
      for (int m = 0; m < 4; ++m) {
        int v2 = ((j4 + m) << 2) + q;
        int idx = (v2 << 9) + ((((k >> 3) ^ (v2 & 7)) << 3) | (k & 7));
        Wis[idx] = f2h(((const float*)&wi4)[m]);
        Whs[idx] = f2h(((const float*)&wh4)[m]);
      }
    }
  }
  __syncthreads();

  // ---------- extract B-fragments to VGPRs (held for the whole kernel) ----------
  const int myv = (w << 4) + l15;
  const int vsw = myv & 7;
  const int rsw = l15 & 7;
  f16x8 bWi[16], bWh[16];
  {
    const ushort_t* wiB = Wis + (myv << 9);
    const ushort_t* whB = Whs + (myv << 9);
    #pragma unroll
    for (int kk = 0; kk < 16; ++kk) {
      const int off = (((kk << 2) + hi) ^ vsw) << 3;
      bWi[kk] = *(const f16x8*)(wiB + off);
      bWh[kk] = *(const f16x8*)(whB + off);
    }
  }

  const int mygc = ((myv & 3) << 9) + colbase + (myv >> 2);
  const float biasv = bi[mygc] + bh[mygc];
  float c = c0[myrow * 512 + mycol];

  const size_t xT_lane = (size_t)(rowbase + l15) * 512 + (hi << 3);
  const float* xf_lane = x + ((size_t)(rowbase + l15) * 1024) * 512 + (hi << 3);
  const ushort_t* hrow = hls + (l15 << 9);

  // x * Wi + bias for step t -> f32x4 (B operand from VGPRs; off the h critical path)
  auto x_gemm = [&](int t) -> f32x4 {
    f32x4 a0 = {biasv, biasv, biasv, biasv}, a1 = {0.f, 0.f, 0.f, 0.f};
    if (XPRE) {
      const ushort_t* xrow = xT + (((size_t)t) << 16) + xT_lane;
      #pragma unroll
      for (int kk = 0; kk < 16; ++kk) {
        f16x8 ax = *(const f16x8*)(xrow + (kk << 5));
        if (kk & 1) a1 = __builtin_amdgcn_mfma_f32_16x16x32_f16(ax, bWi[kk], a1, 0, 0, 0);
        else        a0 = __builtin_amdgcn_mfma_f32_16x16x32_f16(ax, bWi[kk], a0, 0, 0, 0);
      }
    } else {
      const float* xrf = xf_lane + (((size_t)t) << 9);
      #pragma unroll
      for (int kk = 0; kk < 16; ++kk) {
        const int k0 = kk << 5;
        float4 xa = *(const float4*)(xrf + k0);
        float4 xb = *(const float4*)(xrf + k0 + 4);
        f16x8 ax;
        ax[0] = (_Float16)xa.x; ax[1] = (_Float16)xa.y;
        ax[2] = (_Float16)xa.z; ax[3] = (_Float16)xa.w;
        ax[4] = (_Float16)xb.x; ax[5] = (_Float16)xb.y;
        ax[6] = (_Float16)xb.z; ax[7] = (_Float16)xb.w;
        if (kk & 1) a1 = __builtin_amdgcn_mfma_f32_16x16x32_f16(ax, bWi[kk], a1, 0, 0, 0);
        else        a0 = __builtin_amdgcn_mfma_f32_16x16x32_f16(ax, bWi[kk], a0, 0, 0, 0);
      }
    }
    return a0 + a1;
  };

  f32x4 axb = x_gemm(0);

  const uint32* rd0 = hbuf + ((size_t)rg << 13) + (tid << 2);
  const uint32* rd1 = hbuf + ((size_t)(8 + rg) << 13) + (tid << 2);

  // whether this thread's poll words belong to its own block (same for all 8 chunks)
  const bool mine = ((((tid << 2) & 511) & ~15) == colbase);

  for (int t = 0; t < 1024; ++t) {
    // ---- poll h(t) at loop top (round-7 placement) with BATCHED retry ----
    {
      const uint32* base = (t & 1) ? rd1 : rd0;
      const uint32 etag = (uint32)(t + 1);
      u32x4 v[8];
      #pragma unroll
      for (int j = 0; j < 8; ++j) v[j] = ld4t(base + (j << 10), fast);
      waitvm0();
      uint32 pend = 0u;
      #pragma unroll
      for (int j = 0; j < 8; ++j) {
        if (!mine) {
          u32x4 vv = v[j];
          bool ok = ((vv[0] >> 16) == etag) & ((vv[1] >> 16) == etag) &
                    ((vv[2] >> 16) == etag) & ((vv[3] >> 16) == etag);
          if (ok) { UNPACK_CHUNK(j, vv); }
          else    pend |= (1u << j);
        }
      }
      int guard = 0;
      while (pend) {
        if (++guard > (1 << 14)) break;    // wedge -> proceed (wrong answer, no hang)
        if ((guard & 3) == 0) __builtin_amdgcn_s_sleep(1);
        #pragma unroll
        for (int j = 0; j < 8; ++j)
          if (pend & (1u << j)) v[j] = ld4t(base + (j << 10), fast);
        waitvm0();
        #pragma unroll
        for (int j = 0; j < 8; ++j) {
          if (pend & (1u << j)) {
            u32x4 vv = v[j];
            bool ok = ((vv[0] >> 16) == etag) & ((vv[1] >> 16) == etag) &
                      ((vv[2] >> 16) == etag) & ((vv[3] >> 16) == etag);
            if (ok) { UNPACK_CHUNK(j, vv); pend &= ~(1u << j); }
          }
        }
      }
    }
    __syncthreads();   // (A) hls fully staged

    // ---- gates = axb + h*Wh (16 fp16 MFMAs, fp32 accum; B from VGPRs) ----
    f32x4 aH0 = axb, aH1 = {0.f, 0.f, 0.f, 0.f};
    #pragma unroll
    for (int kk = 0; kk < 16; ++kk) {
      f16x8 ah = *(const f16x8*)(hrow + ((((kk << 2) + hi) ^ rsw) << 3));
      if (kk & 1) aH1 = __builtin_amdgcn_mfma_f32_16x16x32_f16(ah, bWh[kk], aH1, 0, 0, 0);
      else        aH0 = __builtin_amdgcn_mfma_f32_16x16x32_f16(ah, bWh[kk], aH0, 0, 0, 0);
    }
    f32x4 acc = aH0 + aH1;
    __syncthreads();   // (B) hls reads done -> next iteration's staging may overwrite

    // ---- gate exchange: per-WAVE LDS slab (in-order DS, no barrier needed) ----
    {
      float* gp = gst + w * 280 + l15 * 17 + (hi << 2);
      gp[0] = acc[0]; gp[1] = acc[1]; gp[2] = acc[2]; gp[3] = acc[3];
    }
    const float* gq = gst + w * 280 + (hi << 2) * 17 + l15;
    const float gI = gq[0], gF = gq[17], gG = gq[34], gO = gq[51];

    const float ig = 1.f / (1.f + __expf(-gI));
    const float fg = 1.f / (1.f + __expf(-gF));
    const float gg = 1.f - 2.f / (1.f + __expf(2.f * gG));
    const float og = 1.f / (1.f + __expf(-gO));
    c = fg * c + ig * gg;
    const float hv = og * (1.f - 2.f / (1.f + __expf(2.f * c)));
    const ushort_t hb = f2h(hv);

    // ---- produce h(t+1): peers via L2 tagged word, own value straight to LDS ----
    if (t < 1023) {
      uint32 word = ((uint32)(t + 2) << 16) | (uint32)hb;
      st1t((t & 1) ? wr0 : wr1, word, fast);
      hls[own_e16] = hb;               // own cols never polled
    }
    out[((size_t)myrow << 19) + ((size_t)t << 9) + mycol] = hv;
    if (t == 1023) {
      out[BTH + (size_t)myrow * 512 + mycol] = hv;            // hy
      out[BTH + 65536 + (size_t)myrow * 512 + mycol] = c;     // cy
    }
    if (t < 1023) axb = x_gemm(t + 1);
  }
}

extern "C" void kernel_launch(void* const* d_in, const int* in_sizes, int n_in,
                              void* d_out, int out_size, void* d_ws, size_t ws_size,
                              hipStream_t stream) {
  const float* x  = (const float*)d_in[0];
  const float* h0 = (const float*)d_in[1];
  const float* c0 = (const float*)d_in[2];
  // d_in[3] = ctx (unused by reference forward)
  const float* Wi = (const float*)d_in[4];
  const float* bi = (const float*)d_in[5];
  const float* Wh = (const float*)d_in[6];
  const float* bh = (const float*)d_in[7];
  float* out = (float*)d_out;

  char* ws = (char*)d_ws;
  uint32* ctrl = (uint32*)ws;                        // 64 B used
  uint32* hbuf = (uint32*)(ws + 4096);               // 512 KB tagged h
  ushort_t* xT = (ushort_t*)(ws + (1u << 20));       // 128 MB fp16 [t][b][k]
  const size_t need_xpre = (1ull << 20) + 134217728ull;
  const bool xpre = ws_size >= need_xpre;

  // zero ctrl + hbuf tags every launch (tags must not survive across replays)
  hipMemsetAsync(ws, 0, 4096 + 524288, stream);

  if (xpre) {
    cvt_xT<<<dim3(32768), dim3(256), 0, stream>>>(x, xT);
  }

  const int LDS_BYTES = 147456 + 4480;               // 151,936 B
  if (xpre) {
    hipFuncSetAttribute((const void*)lstm_rec<true>,
                        hipFuncAttributeMaxDynamicSharedMemorySize, LDS_BYTES);
    void* args[] = {(void*)&x, (void*)&xT, (void*)&h0, (void*)&c0, (void*)&Wi,
                    (void*)&bi, (void*)&Wh, (void*)&bh, (void*)&out,
                    (void*)&hbuf, (void*)&ctrl};
    hipLaunchCooperativeKernel((const void*)lstm_rec<true>, dim3(256), dim3(256),
                               args, LDS_BYTES, stream);
  } else {
    hipFuncSetAttribute((const void*)lstm_rec<false>,
                        hipFuncAttributeMaxDynamicSharedMemorySize, LDS_BYTES);
    void* args[] = {(void*)&x, (void*)&xT, (void*)&h0, (void*)&c0, (void*)&Wi,
                    (void*)&bi, (void*)&Wh, (void*)&bh, (void*)&out,
                    (void*)&hbuf, (void*)&ctrl};
    hipLaunchCooperativeKernel((const void*)lstm_rec<false>, dim3(256), dim3(256),
                               args, LDS_BYTES, stream);
  }
}